// Round 1
// 737.208 us; speedup vs baseline: 1.0036x; 1.0036x over previous
//
#include <hip/hip_runtime.h>
#include <hip/hip_bf16.h>
#include <cstdint>
#include <cstddef>

#define N_NODES 100000
#define N_EDGES 400000
#define IN_CH 1024
#define FEAT_CH 128
#define OUT_CH 3
#define NEG_SLOPE 0.01f
#define NCHUNK 196  // ceil(100000 / 512)

typedef __bf16 bf16x8 __attribute__((ext_vector_type(8)));
typedef unsigned short ushort8v __attribute__((ext_vector_type(8)));
typedef float f32x4 __attribute__((ext_vector_type(4)));

typedef const __attribute__((address_space(1))) unsigned char ga_t;
typedef __attribute__((address_space(3))) unsigned char la_t;
__device__ __forceinline__ void glds16(const void* g, void* l) {
    __builtin_amdgcn_global_load_lds((ga_t*)g, (la_t*)l, 16, 0, 0);
}

// ---------------------------------------------------------------------------
// Wcat[n][k] = bf16( n<128 ? W1_l[k][n] : W1_r[k][n-128] )   [256,1024]
// Also zeroes cnt[] (replaces a hipMemsetAsync dispatch; runs before hist).
// ---------------------------------------------------------------------------
__global__ void wt_kernel(const float* __restrict__ Wl, const float* __restrict__ Wr,
                          unsigned short* __restrict__ Wcat, int* __restrict__ cnt)
{
    int idx = blockIdx.x * blockDim.x + threadIdx.x;
    if (idx < N_NODES) cnt[idx] = 0;
    if (idx >= 256 * IN_CH) return;
    int n = idx >> 10;
    int k = idx & 1023;
    float v = (n < FEAT_CH) ? Wl[k * FEAT_CH + n] : Wr[k * FEAT_CH + (n - FEAT_CH)];
    __bf16 h = (__bf16)v;  // native RNE convert (v_cvt_pk_bf16_f32 path)
    Wcat[idx] = __builtin_bit_cast(unsigned short, h);
}

// ---------------------------------------------------------------------------
// CSR build: histogram of dst
// ---------------------------------------------------------------------------
__global__ void hist_kernel(const int* __restrict__ dst, int* __restrict__ cnt)
{
    int e = blockIdx.x * blockDim.x + threadIdx.x;
    if (e >= N_EDGES) return;
    atomicAdd(&cnt[dst[e]], 1);
}

// ---------------------------------------------------------------------------
// Parallel exclusive scan, phase 1: per-chunk (512 elems) exclusive scan
// ---------------------------------------------------------------------------
__global__ __launch_bounds__(256) void scan_p1(const int* __restrict__ cnt,
                                               int* __restrict__ rowptr,
                                               int* __restrict__ bsum)
{
    __shared__ int sdata[256];
    const int t = threadIdx.x;
    const int c0 = blockIdx.x * 512;
    const int i0 = c0 + 2 * t;
    int v0 = (i0     < N_NODES) ? cnt[i0]     : 0;
    int v1 = (i0 + 1 < N_NODES) ? cnt[i0 + 1] : 0;
    int s = v0 + v1;
    sdata[t] = s;
    __syncthreads();
    #pragma unroll
    for (int off = 1; off < 256; off <<= 1) {
        int tmp = (t >= off) ? sdata[t - off] : 0;
        __syncthreads();
        sdata[t] += tmp;
        __syncthreads();
    }
    int ex = sdata[t] - s;  // exclusive prefix within chunk
    if (i0     < N_NODES) rowptr[i0]     = ex;
    if (i0 + 1 < N_NODES) rowptr[i0 + 1] = ex + v0;
    if (t == 255) bsum[blockIdx.x] = sdata[255];
}

// phase 2: exclusive scan of 196 block sums (single block)
__global__ __launch_bounds__(256) void scan_p2(const int* __restrict__ bsum,
                                               int* __restrict__ boff)
{
    __shared__ int sdata[256];
    const int t = threadIdx.x;
    int v = (t < NCHUNK) ? bsum[t] : 0;
    sdata[t] = v;
    __syncthreads();
    #pragma unroll
    for (int off = 1; off < 256; off <<= 1) {
        int tmp = (t >= off) ? sdata[t - off] : 0;
        __syncthreads();
        sdata[t] += tmp;
        __syncthreads();
    }
    if (t < NCHUNK) boff[t] = sdata[t] - v;
}

// phase 3: add chunk offsets; also emit rowptr_work (the scatter cursor copy,
// replacing the separate cursor buffer + its memset).
__global__ void scan_p3(int* __restrict__ rowptr, const int* __restrict__ boff,
                        int* __restrict__ rowptr_work)
{
    const int c0 = blockIdx.x * 512;
    const int add = boff[blockIdx.x];
    const int t = threadIdx.x;
    int i0 = c0 + 2 * t;
    if (i0 < N_NODES) {
        int v = rowptr[i0] + add;
        rowptr[i0] = v; rowptr_work[i0] = v;
    }
    if (i0 + 1 < N_NODES) {
        int v = rowptr[i0 + 1] + add;
        rowptr[i0 + 1] = v; rowptr_work[i0 + 1] = v;
    }
    if (blockIdx.x == 0 && t == 0) rowptr[N_NODES] = N_EDGES;
}

// ---------------------------------------------------------------------------
// CSR build: place src into dst-sorted order (atomic cursor = rowptr_work)
// ---------------------------------------------------------------------------
__global__ void scatter_edges(const int* __restrict__ src, const int* __restrict__ dst,
                              int* __restrict__ rowptr_work,
                              int* __restrict__ sorted_src)
{
    int e = blockIdx.x * blockDim.x + threadIdx.x;
    if (e >= N_EDGES) return;
    int pos = atomicAdd(&rowptr_work[dst[e]], 1);
    sorted_src[pos] = src[e];
}

// ---------------------------------------------------------------------------
// Fused GEMM: [Yl | Yr] = X[100000,1024] @ [W1_l | W1_r]   (bf16 MFMA)
// Tile 128 rows x 256 cols, BK=64, 256 threads (4 waves, 2x2).
// A: fp32 -> register prefetch -> native cvt_pk bf16 -> XOR-swizzled LDS.
// B: bf16 Wcat via global_load_lds width=16 (unpadded layout).
// ---------------------------------------------------------------------------
__global__ __launch_bounds__(256, 2) void gemm_fused(
    const float* __restrict__ X, const unsigned short* __restrict__ Wcat,
    float* __restrict__ Yl, float* __restrict__ Yr)
{
    __shared__ unsigned short As[128 * 64];  // [row][chunk^(row&7)] chunks of 8 bf16
    __shared__ unsigned short Bs[256 * 64];  // [n][k] unpadded (glds layout)

    const int tid   = threadIdx.x;
    const int lane  = tid & 63;
    const int wave  = tid >> 6;
    const int waveM = wave >> 1;
    const int waveN = wave & 1;
    const int q     = lane >> 4;
    const int l16   = lane & 15;
    const int esw   = l16 & 7;         // read-side swizzle key
    const int row0  = blockIdx.x * 128;

    const int arow = tid >> 3;          // 0..31 (+32p)
    const int au   = tid & 7;           // A chunk
    const int aesw = arow & 7;          // write-side swizzle key

    f32x4 acc[4][8] = {};
    float4 pre[8];

    // OOB rows (only in the last of 782 blocks) are clamped to row N-1:
    // their MFMA results are garbage-but-finite and masked at the store.
    auto prefetchA = [&](int k0) {
        #pragma unroll
        for (int p = 0; p < 4; ++p) {
            int grow = row0 + p * 32 + arow;
            grow = grow < N_NODES ? grow : (N_NODES - 1);
            const float* gp = &X[(size_t)grow * IN_CH + k0 + au * 8];
            pre[2 * p]     = *(const float4*)gp;
            pre[2 * p + 1] = *(const float4*)(gp + 4);
        }
    };

    prefetchA(0);

    for (int kt = 0; kt < IN_CH / 64; ++kt) {
        const int k0 = kt * 64;

        // ---- B: async global->LDS, 8 issues/wave, 8 rows (1 KB) per issue ----
        #pragma unroll
        for (int i = 0; i < 8; ++i) {
            const int gi = wave * 8 + i;                   // 0..31
            const int r  = gi * 8 + (lane >> 3);
            glds16(&Wcat[(size_t)r * IN_CH + k0 + (lane & 7) * 8],
                   &Bs[gi * 8 * 64]);
        }

        // ---- A: native packed f32->bf16 convert, swizzled LDS write ----
        #pragma unroll
        for (int p = 0; p < 4; ++p) {
            const int row = p * 32 + arow;
            const int c   = au ^ aesw;
            const float4 a = pre[2 * p], b = pre[2 * p + 1];
            bf16x8 o;
            o[0] = (__bf16)a.x; o[1] = (__bf16)a.y;
            o[2] = (__bf16)a.z; o[3] = (__bf16)a.w;
            o[4] = (__bf16)b.x; o[5] = (__bf16)b.y;
            o[6] = (__bf16)b.z; o[7] = (__bf16)b.w;
            *(bf16x8*)&As[row * 64 + c * 8] = o;
        }

        if (kt + 1 < IN_CH / 64) prefetchA(k0 + 64);

        __syncthreads();

        // ---- MFMA: 2 k-steps of 32, 4x8 tiles per wave ----
        #pragma unroll
        for (int s = 0; s < 2; ++s) {
            bf16x8 af[4], bfr[8];
            const int kc = q + 4 * s;   // chunk index 0..7
            #pragma unroll
            for (int mi = 0; mi < 4; ++mi) {
                const int m = waveM * 64 + mi * 16 + l16;
                af[mi] = __builtin_bit_cast(
                    bf16x8, *(const ushort8v*)&As[m * 64 + (kc ^ esw) * 8]);
            }
            #pragma unroll
            for (int ni = 0; ni < 8; ++ni) {
                const int n = waveN * 128 + ni * 16 + l16;
                bfr[ni] = __builtin_bit_cast(
                    bf16x8, *(const ushort8v*)&Bs[n * 64 + kc * 8]);
            }
            #pragma unroll
            for (int mi = 0; mi < 4; ++mi)
                #pragma unroll
                for (int ni = 0; ni < 8; ++ni)
                    acc[mi][ni] = __builtin_amdgcn_mfma_f32_16x16x32_bf16(
                        af[mi], bfr[ni], acc[mi][ni], 0, 0, 0);
        }
        __syncthreads();
    }

    // ---- epilogue: waveN=0 -> Yl, waveN=1 -> Yr ----
    float* __restrict__ Ybuf = waveN ? Yr : Yl;
    #pragma unroll
    for (int mi = 0; mi < 4; ++mi) {
        #pragma unroll
        for (int r = 0; r < 4; ++r) {
            const int grow = row0 + waveM * 64 + mi * 16 + q * 4 + r;
            if (grow < N_NODES) {
                #pragma unroll
                for (int ni = 0; ni < 8; ++ni)
                    Ybuf[(size_t)grow * FEAT_CH + ni * 16 + l16] = acc[mi][ni][r];
            }
        }
    }
}

// ---------------------------------------------------------------------------
// Fused layer-1 aggregation + combine + layer-2 projection.
// One wave per node; lane holds channels 2l, 2l+1.
// h = leaky( (sum Yl[src]) / max(deg,1) + Yr[node] + b1 )  (in registers)
// Zl = h @ W2_l, Zr = h @ W2_r  via shuffle reduction.
// ---------------------------------------------------------------------------
__global__ __launch_bounds__(256) void fused_agg(
    const float* __restrict__ Yl, const float* __restrict__ Yr,
    const int* __restrict__ rowptr, const int* __restrict__ sorted_src,
    const float* __restrict__ b1,
    const float* __restrict__ W2l, const float* __restrict__ W2r,
    float* __restrict__ Zl, float* __restrict__ Zr)
{
    int gid = blockIdx.x * blockDim.x + threadIdx.x;
    int node = gid >> 6;
    if (node >= N_NODES) return;
    int lane = threadIdx.x & 63;

    int beg = rowptr[node], end = rowptr[node + 1];
    float ax = 0.f, ay = 0.f;
    for (int e = beg; e < end; ++e) {
        int s = sorted_src[e];
        float2 v = *(const float2*)&Yl[(size_t)s * FEAT_CH + lane * 2];
        ax += v.x; ay += v.y;
    }
    float invd = 1.0f / fmaxf((float)(end - beg), 1.0f);
    float2 y  = *(const float2*)&Yr[(size_t)node * FEAT_CH + lane * 2];
    float2 bb = *(const float2*)&b1[lane * 2];
    float hx = fmaf(ax, invd, y.x) + bb.x;
    float hy = fmaf(ay, invd, y.y) + bb.y;
    hx = hx >= 0.f ? hx : NEG_SLOPE * hx;
    hy = hy >= 0.f ? hy : NEG_SLOPE * hy;

    const float* wl = &W2l[lane * 2 * 3];
    const float* wr = &W2r[lane * 2 * 3];
    float z[6];
    #pragma unroll
    for (int c = 0; c < 3; ++c) {
        z[c]     = hx * wl[c] + hy * wl[3 + c];
        z[3 + c] = hx * wr[c] + hy * wr[3 + c];
    }
    #pragma unroll
    for (int off = 32; off >= 1; off >>= 1)
        #pragma unroll
        for (int c = 0; c < 6; ++c)
            z[c] += __shfl_xor(z[c], off);

    if (lane == 0) {
        Zl[node * 3 + 0] = z[0]; Zl[node * 3 + 1] = z[1]; Zl[node * 3 + 2] = z[2];
        Zr[node * 3 + 0] = z[3]; Zr[node * 3 + 1] = z[4]; Zr[node * 3 + 2] = z[5];
    }
}

// ---------------------------------------------------------------------------
// Layer-2 aggregation (gather) + final combine, one thread per node:
// out[n,:] = (sum Zl[src,:]) / max(deg,1) + Zr[n,:] + b2[:]
// ---------------------------------------------------------------------------
__global__ void agg2_final(const float* __restrict__ Zl, const float* __restrict__ Zr,
                           const int* __restrict__ rowptr, const int* __restrict__ sorted_src,
                           const float* __restrict__ b2, float* __restrict__ out)
{
    int node = blockIdx.x * blockDim.x + threadIdx.x;
    if (node >= N_NODES) return;
    int beg = rowptr[node], end = rowptr[node + 1];
    float a0 = 0.f, a1 = 0.f, a2 = 0.f;
    for (int e = beg; e < end; ++e) {
        const float* zp = &Zl[sorted_src[e] * 3];
        a0 += zp[0]; a1 += zp[1]; a2 += zp[2];
    }
    float invd = 1.0f / fmaxf((float)(end - beg), 1.0f);
    out[node * 3 + 0] = fmaf(a0, invd, Zr[node * 3 + 0]) + b2[0];
    out[node * 3 + 1] = fmaf(a1, invd, Zr[node * 3 + 1]) + b2[1];
    out[node * 3 + 2] = fmaf(a2, invd, Zr[node * 3 + 2]) + b2[2];
}

// ---------------------------------------------------------------------------
extern "C" void kernel_launch(void* const* d_in, const int* in_sizes, int n_in,
                              void* d_out, int out_size, void* d_ws, size_t ws_size,
                              hipStream_t stream)
{
    const float* X   = (const float*)d_in[0];
    const int*   e2  = (const int*)d_in[2];     // edges2 [2, E] int32
    const float* W1l = (const float*)d_in[5];
    const float* W1r = (const float*)d_in[6];
    const float* b1  = (const float*)d_in[7];
    const float* W2l = (const float*)d_in[8];
    const float* W2r = (const float*)d_in[9];
    const float* b2  = (const float*)d_in[10];
    const int* src = e2;
    const int* dst = e2 + N_EDGES;

    char* ws = (char*)d_ws;
    size_t off = 0;
    auto alloc = [&](size_t bytes) -> void* {
        void* p = ws + off;
        off += (bytes + 255) & ~(size_t)255;
        return p;
    };
    const size_t NB = (size_t)N_NODES * FEAT_CH * sizeof(float);  // 51.2 MB
    float* Yl = (float*)alloc(NB);
    float* Yr = (float*)alloc(NB);
    float* Zl = (float*)alloc((size_t)N_NODES * OUT_CH * sizeof(float));
    float* Zr = (float*)alloc((size_t)N_NODES * OUT_CH * sizeof(float));
    unsigned short* Wcat = (unsigned short*)alloc((size_t)256 * IN_CH * 2);
    int* cnt         = (int*)alloc((size_t)N_NODES * sizeof(int));
    int* rowptr      = (int*)alloc((size_t)(N_NODES + 1) * sizeof(int));
    int* rowptr_work = (int*)alloc((size_t)N_NODES * sizeof(int));
    int* bsum        = (int*)alloc((size_t)NCHUNK * sizeof(int));
    int* boff        = (int*)alloc((size_t)NCHUNK * sizeof(int));
    int* sorted_src  = (int*)alloc((size_t)N_EDGES * sizeof(int));

    // --- weights + cnt zeroing (no memset dispatches) ---
    wt_kernel<<<(256 * IN_CH + 255) / 256, 256, 0, stream>>>(W1l, W1r, Wcat, cnt);

    // --- CSR (counting sort by dst, parallel scan) ---
    hist_kernel<<<(N_EDGES + 255) / 256, 256, 0, stream>>>(dst, cnt);
    scan_p1<<<NCHUNK, 256, 0, stream>>>(cnt, rowptr, bsum);
    scan_p2<<<1, 256, 0, stream>>>(bsum, boff);
    scan_p3<<<NCHUNK, 256, 0, stream>>>(rowptr, boff, rowptr_work);
    scatter_edges<<<(N_EDGES + 255) / 256, 256, 0, stream>>>(src, dst, rowptr_work,
                                                             sorted_src);

    // --- layer 1 GEMM (fused Yl/Yr) ---
    gemm_fused<<<(N_NODES + 127) / 128, 256, 0, stream>>>(X, Wcat, Yl, Yr);

    // --- fused aggregation + combine + layer-2 projection ---
    fused_agg<<<(N_NODES * 64) / 256, 256, 0, stream>>>(Yl, Yr, rowptr, sorted_src,
                                                        b1, W2l, W2r, Zl, Zr);

    // --- layer-2 aggregation + output ---
    agg2_final<<<(N_NODES + 255) / 256, 256, 0, stream>>>(Zl, Zr, rowptr, sorted_src,
                                                          b2, (float*)d_out);
}

// Round 2
// 723.324 us; speedup vs baseline: 1.0228x; 1.0192x over previous
//
#include <hip/hip_runtime.h>
#include <hip/hip_bf16.h>
#include <cstdint>
#include <cstddef>

#define N_NODES 100000
#define N_EDGES 400000
#define IN_CH 1024
#define FEAT_CH 128
#define OUT_CH 3
#define NEG_SLOPE 0.01f
#define NCHUNK 196  // ceil(100000 / 512)

typedef __bf16 bf16x8 __attribute__((ext_vector_type(8)));
typedef unsigned short ushort8v __attribute__((ext_vector_type(8)));
typedef float f32x4 __attribute__((ext_vector_type(4)));

typedef const __attribute__((address_space(1))) unsigned char ga_t;
typedef __attribute__((address_space(3))) unsigned char la_t;
__device__ __forceinline__ void glds16(const void* g, void* l) {
    __builtin_amdgcn_global_load_lds((ga_t*)g, (la_t*)l, 16, 0, 0);
}

__device__ __forceinline__ unsigned short f2bf(float f) {
    __bf16 h = (__bf16)f;  // native RNE
    return __builtin_bit_cast(unsigned short, h);
}
__device__ __forceinline__ float bf2f(unsigned short u) {
    return __uint_as_float((unsigned)u << 16);
}

// ---------------------------------------------------------------------------
// Wcat[n][k] = bf16( n<128 ? W1_l[k][n] : W1_r[k][n-128] )   [256,1024]
// Also zeroes cnt[] (replaces a hipMemsetAsync dispatch; runs before hist).
// ---------------------------------------------------------------------------
__global__ void wt_kernel(const float* __restrict__ Wl, const float* __restrict__ Wr,
                          unsigned short* __restrict__ Wcat, int* __restrict__ cnt)
{
    int idx = blockIdx.x * blockDim.x + threadIdx.x;
    if (idx < N_NODES) cnt[idx] = 0;
    if (idx >= 256 * IN_CH) return;
    int n = idx >> 10;
    int k = idx & 1023;
    float v = (n < FEAT_CH) ? Wl[k * FEAT_CH + n] : Wr[k * FEAT_CH + (n - FEAT_CH)];
    Wcat[idx] = f2bf(v);
}

// ---------------------------------------------------------------------------
// CSR build: histogram of dst
// ---------------------------------------------------------------------------
__global__ void hist_kernel(const int* __restrict__ dst, int* __restrict__ cnt)
{
    int e = blockIdx.x * blockDim.x + threadIdx.x;
    if (e >= N_EDGES) return;
    atomicAdd(&cnt[dst[e]], 1);
}

// ---------------------------------------------------------------------------
// Parallel exclusive scan, phase 1: per-chunk (512 elems) exclusive scan
// ---------------------------------------------------------------------------
__global__ __launch_bounds__(256) void scan_p1(const int* __restrict__ cnt,
                                               int* __restrict__ rowptr,
                                               int* __restrict__ bsum)
{
    __shared__ int sdata[256];
    const int t = threadIdx.x;
    const int c0 = blockIdx.x * 512;
    const int i0 = c0 + 2 * t;
    int v0 = (i0     < N_NODES) ? cnt[i0]     : 0;
    int v1 = (i0 + 1 < N_NODES) ? cnt[i0 + 1] : 0;
    int s = v0 + v1;
    sdata[t] = s;
    __syncthreads();
    #pragma unroll
    for (int off = 1; off < 256; off <<= 1) {
        int tmp = (t >= off) ? sdata[t - off] : 0;
        __syncthreads();
        sdata[t] += tmp;
        __syncthreads();
    }
    int ex = sdata[t] - s;  // exclusive prefix within chunk
    if (i0     < N_NODES) rowptr[i0]     = ex;
    if (i0 + 1 < N_NODES) rowptr[i0 + 1] = ex + v0;
    if (t == 255) bsum[blockIdx.x] = sdata[255];
}

// phases 2+3 merged: each of the 196 blocks reduces its own chunk offset
// (sum of bsum[0..blk-1], a 196-element reduction) and applies it; also emits
// rowptr_work (the scatter cursor copy).
__global__ __launch_bounds__(256) void scan_p23(int* __restrict__ rowptr,
                                                const int* __restrict__ bsum,
                                                int* __restrict__ rowptr_work)
{
    __shared__ int wsum[4];
    const int t = threadIdx.x;
    int v = (t < (int)blockIdx.x) ? bsum[t] : 0;  // blockIdx.x <= 195 < NCHUNK
    #pragma unroll
    for (int off = 32; off >= 1; off >>= 1) v += __shfl_xor(v, off);
    if ((t & 63) == 0) wsum[t >> 6] = v;
    __syncthreads();
    const int add = wsum[0] + wsum[1] + wsum[2] + wsum[3];
    const int i0 = blockIdx.x * 512 + 2 * t;
    if (i0 < N_NODES) {
        int r = rowptr[i0] + add;
        rowptr[i0] = r; rowptr_work[i0] = r;
    }
    if (i0 + 1 < N_NODES) {
        int r = rowptr[i0 + 1] + add;
        rowptr[i0 + 1] = r; rowptr_work[i0 + 1] = r;
    }
    if (blockIdx.x == 0 && t == 0) rowptr[N_NODES] = N_EDGES;
}

// ---------------------------------------------------------------------------
// CSR build: place src into dst-sorted order (atomic cursor = rowptr_work)
// ---------------------------------------------------------------------------
__global__ void scatter_edges(const int* __restrict__ src, const int* __restrict__ dst,
                              int* __restrict__ rowptr_work,
                              int* __restrict__ sorted_src)
{
    int e = blockIdx.x * blockDim.x + threadIdx.x;
    if (e >= N_EDGES) return;
    int pos = atomicAdd(&rowptr_work[dst[e]], 1);
    sorted_src[pos] = src[e];
}

// ---------------------------------------------------------------------------
// Fused GEMM: [Yl | Yr] = X[100000,1024] @ [W1_l | W1_r]   (bf16 MFMA)
// Tile 128 rows x 256 cols, BK=64, 256 threads (4 waves, 2x2).
// A: fp32 -> register prefetch -> native cvt bf16 -> XOR-swizzled LDS.
// B: bf16 Wcat via global_load_lds width=16 (unpadded layout).
// Outputs stored bf16 (halves HBM write + downstream read/gather bytes).
// ---------------------------------------------------------------------------
__global__ __launch_bounds__(256, 2) void gemm_fused(
    const float* __restrict__ X, const unsigned short* __restrict__ Wcat,
    unsigned short* __restrict__ Ylb, unsigned short* __restrict__ Yrb)
{
    __shared__ unsigned short As[128 * 64];  // [row][chunk^(row&7)] chunks of 8 bf16
    __shared__ unsigned short Bs[256 * 64];  // [n][k] unpadded (glds layout)

    const int tid   = threadIdx.x;
    const int lane  = tid & 63;
    const int wave  = tid >> 6;
    const int waveM = wave >> 1;
    const int waveN = wave & 1;
    const int q     = lane >> 4;
    const int l16   = lane & 15;
    const int esw   = l16 & 7;         // read-side swizzle key
    const int row0  = blockIdx.x * 128;

    const int arow = tid >> 3;          // 0..31 (+32p)
    const int au   = tid & 7;           // A chunk
    const int aesw = arow & 7;          // write-side swizzle key

    f32x4 acc[4][8] = {};
    float4 pre[8];

    // OOB rows (only in the last of 782 blocks) are clamped to row N-1:
    // their MFMA results are garbage-but-finite and masked at the store.
    auto prefetchA = [&](int k0) {
        #pragma unroll
        for (int p = 0; p < 4; ++p) {
            int grow = row0 + p * 32 + arow;
            grow = grow < N_NODES ? grow : (N_NODES - 1);
            const float* gp = &X[(size_t)grow * IN_CH + k0 + au * 8];
            pre[2 * p]     = *(const float4*)gp;
            pre[2 * p + 1] = *(const float4*)(gp + 4);
        }
    };

    prefetchA(0);

    for (int kt = 0; kt < IN_CH / 64; ++kt) {
        const int k0 = kt * 64;

        // ---- B: async global->LDS, 8 issues/wave, 8 rows (1 KB) per issue ----
        #pragma unroll
        for (int i = 0; i < 8; ++i) {
            const int gi = wave * 8 + i;                   // 0..31
            const int r  = gi * 8 + (lane >> 3);
            glds16(&Wcat[(size_t)r * IN_CH + k0 + (lane & 7) * 8],
                   &Bs[gi * 8 * 64]);
        }

        // ---- A: native packed f32->bf16 convert, swizzled LDS write ----
        #pragma unroll
        for (int p = 0; p < 4; ++p) {
            const int row = p * 32 + arow;
            const int c   = au ^ aesw;
            const float4 a = pre[2 * p], b = pre[2 * p + 1];
            bf16x8 o;
            o[0] = (__bf16)a.x; o[1] = (__bf16)a.y;
            o[2] = (__bf16)a.z; o[3] = (__bf16)a.w;
            o[4] = (__bf16)b.x; o[5] = (__bf16)b.y;
            o[6] = (__bf16)b.z; o[7] = (__bf16)b.w;
            *(bf16x8*)&As[row * 64 + c * 8] = o;
        }

        if (kt + 1 < IN_CH / 64) prefetchA(k0 + 64);

        __syncthreads();

        // ---- MFMA: 2 k-steps of 32, 4x8 tiles per wave ----
        #pragma unroll
        for (int s = 0; s < 2; ++s) {
            bf16x8 af[4], bfr[8];
            const int kc = q + 4 * s;   // chunk index 0..7
            #pragma unroll
            for (int mi = 0; mi < 4; ++mi) {
                const int m = waveM * 64 + mi * 16 + l16;
                af[mi] = __builtin_bit_cast(
                    bf16x8, *(const ushort8v*)&As[m * 64 + (kc ^ esw) * 8]);
            }
            #pragma unroll
            for (int ni = 0; ni < 8; ++ni) {
                const int n = waveN * 128 + ni * 16 + l16;
                bfr[ni] = __builtin_bit_cast(
                    bf16x8, *(const ushort8v*)&Bs[n * 64 + kc * 8]);
            }
            #pragma unroll
            for (int mi = 0; mi < 4; ++mi)
                #pragma unroll
                for (int ni = 0; ni < 8; ++ni)
                    acc[mi][ni] = __builtin_amdgcn_mfma_f32_16x16x32_bf16(
                        af[mi], bfr[ni], acc[mi][ni], 0, 0, 0);
        }
        __syncthreads();
    }

    // ---- epilogue: waveN=0 -> Ylb, waveN=1 -> Yrb (bf16 RNE) ----
    unsigned short* __restrict__ Ybuf = waveN ? Yrb : Ylb;
    #pragma unroll
    for (int mi = 0; mi < 4; ++mi) {
        #pragma unroll
        for (int r = 0; r < 4; ++r) {
            const int grow = row0 + waveM * 64 + mi * 16 + q * 4 + r;
            if (grow < N_NODES) {
                #pragma unroll
                for (int ni = 0; ni < 8; ++ni)
                    Ybuf[(size_t)grow * FEAT_CH + ni * 16 + l16] =
                        f2bf(acc[mi][ni][r]);
            }
        }
    }
}

// ---------------------------------------------------------------------------
// Fused layer-1 aggregation + combine + layer-2 projection.
// One wave per node; lane holds channels 2l, 2l+1 (bf16 inputs, f32 math).
// h = leaky( (sum Yl[src]) / max(deg,1) + Yr[node] + b1 )  (in registers)
// Zl = h @ W2_l, Zr = h @ W2_r  via shuffle reduction.
// ---------------------------------------------------------------------------
__global__ __launch_bounds__(256) void fused_agg(
    const unsigned short* __restrict__ Ylb, const unsigned short* __restrict__ Yrb,
    const int* __restrict__ rowptr, const int* __restrict__ sorted_src,
    const float* __restrict__ b1,
    const float* __restrict__ W2l, const float* __restrict__ W2r,
    float* __restrict__ Zl, float* __restrict__ Zr)
{
    int gid = blockIdx.x * blockDim.x + threadIdx.x;
    int node = gid >> 6;
    if (node >= N_NODES) return;
    int lane = threadIdx.x & 63;

    int beg = rowptr[node], end = rowptr[node + 1];
    float ax = 0.f, ay = 0.f;
    for (int e = beg; e < end; ++e) {
        int s = sorted_src[e];
        ushort2 v = *(const ushort2*)&Ylb[(size_t)s * FEAT_CH + lane * 2];
        ax += bf2f(v.x); ay += bf2f(v.y);
    }
    float invd = 1.0f / fmaxf((float)(end - beg), 1.0f);
    ushort2 yv = *(const ushort2*)&Yrb[(size_t)node * FEAT_CH + lane * 2];
    float2 bb = *(const float2*)&b1[lane * 2];
    float hx = fmaf(ax, invd, bf2f(yv.x)) + bb.x;
    float hy = fmaf(ay, invd, bf2f(yv.y)) + bb.y;
    hx = hx >= 0.f ? hx : NEG_SLOPE * hx;
    hy = hy >= 0.f ? hy : NEG_SLOPE * hy;

    const float* wl = &W2l[lane * 2 * 3];
    const float* wr = &W2r[lane * 2 * 3];
    float z[6];
    #pragma unroll
    for (int c = 0; c < 3; ++c) {
        z[c]     = hx * wl[c] + hy * wl[3 + c];
        z[3 + c] = hx * wr[c] + hy * wr[3 + c];
    }
    #pragma unroll
    for (int off = 32; off >= 1; off >>= 1)
        #pragma unroll
        for (int c = 0; c < 6; ++c)
            z[c] += __shfl_xor(z[c], off);

    if (lane == 0) {
        Zl[node * 3 + 0] = z[0]; Zl[node * 3 + 1] = z[1]; Zl[node * 3 + 2] = z[2];
        Zr[node * 3 + 0] = z[3]; Zr[node * 3 + 1] = z[4]; Zr[node * 3 + 2] = z[5];
    }
}

// ---------------------------------------------------------------------------
// Layer-2 aggregation (gather) + final combine, one thread per node:
// out[n,:] = (sum Zl[src,:]) / max(deg,1) + Zr[n,:] + b2[:]
// ---------------------------------------------------------------------------
__global__ void agg2_final(const float* __restrict__ Zl, const float* __restrict__ Zr,
                           const int* __restrict__ rowptr, const int* __restrict__ sorted_src,
                           const float* __restrict__ b2, float* __restrict__ out)
{
    int node = blockIdx.x * blockDim.x + threadIdx.x;
    if (node >= N_NODES) return;
    int beg = rowptr[node], end = rowptr[node + 1];
    float a0 = 0.f, a1 = 0.f, a2 = 0.f;
    for (int e = beg; e < end; ++e) {
        const float* zp = &Zl[sorted_src[e] * 3];
        a0 += zp[0]; a1 += zp[1]; a2 += zp[2];
    }
    float invd = 1.0f / fmaxf((float)(end - beg), 1.0f);
    out[node * 3 + 0] = fmaf(a0, invd, Zr[node * 3 + 0]) + b2[0];
    out[node * 3 + 1] = fmaf(a1, invd, Zr[node * 3 + 1]) + b2[1];
    out[node * 3 + 2] = fmaf(a2, invd, Zr[node * 3 + 2]) + b2[2];
}

// ---------------------------------------------------------------------------
extern "C" void kernel_launch(void* const* d_in, const int* in_sizes, int n_in,
                              void* d_out, int out_size, void* d_ws, size_t ws_size,
                              hipStream_t stream)
{
    const float* X   = (const float*)d_in[0];
    const int*   e2  = (const int*)d_in[2];     // edges2 [2, E] int32
    const float* W1l = (const float*)d_in[5];
    const float* W1r = (const float*)d_in[6];
    const float* b1  = (const float*)d_in[7];
    const float* W2l = (const float*)d_in[8];
    const float* W2r = (const float*)d_in[9];
    const float* b2  = (const float*)d_in[10];
    const int* src = e2;
    const int* dst = e2 + N_EDGES;

    char* ws = (char*)d_ws;
    size_t off = 0;
    auto alloc = [&](size_t bytes) -> void* {
        void* p = ws + off;
        off += (bytes + 255) & ~(size_t)255;
        return p;
    };
    const size_t NBH = (size_t)N_NODES * FEAT_CH * sizeof(unsigned short);  // 25.6 MB
    unsigned short* Ylb = (unsigned short*)alloc(NBH);
    unsigned short* Yrb = (unsigned short*)alloc(NBH);
    float* Zl = (float*)alloc((size_t)N_NODES * OUT_CH * sizeof(float));
    float* Zr = (float*)alloc((size_t)N_NODES * OUT_CH * sizeof(float));
    unsigned short* Wcat = (unsigned short*)alloc((size_t)256 * IN_CH * 2);
    int* cnt         = (int*)alloc((size_t)N_NODES * sizeof(int));
    int* rowptr      = (int*)alloc((size_t)(N_NODES + 1) * sizeof(int));
    int* rowptr_work = (int*)alloc((size_t)N_NODES * sizeof(int));
    int* bsum        = (int*)alloc((size_t)NCHUNK * sizeof(int));
    int* sorted_src  = (int*)alloc((size_t)N_EDGES * sizeof(int));

    // --- weights + cnt zeroing (no memset dispatches) ---
    wt_kernel<<<(256 * IN_CH + 255) / 256, 256, 0, stream>>>(W1l, W1r, Wcat, cnt);

    // --- CSR (counting sort by dst, parallel scan) ---
    hist_kernel<<<(N_EDGES + 255) / 256, 256, 0, stream>>>(dst, cnt);
    scan_p1<<<NCHUNK, 256, 0, stream>>>(cnt, rowptr, bsum);
    scan_p23<<<NCHUNK, 256, 0, stream>>>(rowptr, bsum, rowptr_work);
    scatter_edges<<<(N_EDGES + 255) / 256, 256, 0, stream>>>(src, dst, rowptr_work,
                                                             sorted_src);

    // --- layer 1 GEMM (fused Yl/Yr, bf16 outputs) ---
    gemm_fused<<<(N_NODES + 127) / 128, 256, 0, stream>>>(X, Wcat, Ylb, Yrb);

    // --- fused aggregation + combine + layer-2 projection ---
    fused_agg<<<(N_NODES * 64) / 256, 256, 0, stream>>>(Ylb, Yrb, rowptr, sorted_src,
                                                        b1, W2l, W2r, Zl, Zr);

    // --- layer-2 aggregation + output ---
    agg2_final<<<(N_NODES + 255) / 256, 256, 0, stream>>>(Zl, Zr, rowptr, sorted_src,
                                                          b2, (float*)d_out);
}

// Round 3
// 720.642 us; speedup vs baseline: 1.0266x; 1.0037x over previous
//
#include <hip/hip_runtime.h>
#include <hip/hip_bf16.h>
#include <cstdint>
#include <cstddef>

#define N_NODES 100000
#define N_EDGES 400000
#define IN_CH 1024
#define FEAT_CH 128
#define OUT_CH 3
#define NEG_SLOPE 0.01f
#define NCHUNK 196  // ceil(100000 / 512)

typedef __bf16 bf16x8 __attribute__((ext_vector_type(8)));
typedef unsigned short ushort8v __attribute__((ext_vector_type(8)));
typedef float f32x4 __attribute__((ext_vector_type(4)));

typedef const __attribute__((address_space(1))) unsigned char ga_t;
typedef __attribute__((address_space(3))) unsigned char la_t;
__device__ __forceinline__ void glds16(const void* g, void* l) {
    __builtin_amdgcn_global_load_lds((ga_t*)g, (la_t*)l, 16, 0, 0);
}

__device__ __forceinline__ unsigned short f2bf(float f) {
    __bf16 h = (__bf16)f;  // native RNE
    return __builtin_bit_cast(unsigned short, h);
}
__device__ __forceinline__ float bf2f(unsigned short u) {
    return __uint_as_float((unsigned)u << 16);
}

// ---------------------------------------------------------------------------
// Wcat[n][k] = bf16( n<128 ? W1_l[k][n] : W1_r[k][n-128] )   [256,1024]
// Also zeroes cnt[] (replaces a hipMemsetAsync dispatch; runs before hist).
// ---------------------------------------------------------------------------
__global__ void wt_kernel(const float* __restrict__ Wl, const float* __restrict__ Wr,
                          unsigned short* __restrict__ Wcat, int* __restrict__ cnt)
{
    int idx = blockIdx.x * blockDim.x + threadIdx.x;
    if (idx < N_NODES) cnt[idx] = 0;
    if (idx >= 256 * IN_CH) return;
    int n = idx >> 10;
    int k = idx & 1023;
    float v = (n < FEAT_CH) ? Wl[k * FEAT_CH + n] : Wr[k * FEAT_CH + (n - FEAT_CH)];
    Wcat[idx] = f2bf(v);
}

// ---------------------------------------------------------------------------
// CSR build: histogram of dst
// ---------------------------------------------------------------------------
__global__ void hist_kernel(const int* __restrict__ dst, int* __restrict__ cnt)
{
    int e = blockIdx.x * blockDim.x + threadIdx.x;
    if (e >= N_EDGES) return;
    atomicAdd(&cnt[dst[e]], 1);
}

// ---------------------------------------------------------------------------
// Parallel exclusive scan, phase 1: per-chunk (512 elems) exclusive scan
// ---------------------------------------------------------------------------
__global__ __launch_bounds__(256) void scan_p1(const int* __restrict__ cnt,
                                               int* __restrict__ rowptr,
                                               int* __restrict__ bsum)
{
    __shared__ int sdata[256];
    const int t = threadIdx.x;
    const int c0 = blockIdx.x * 512;
    const int i0 = c0 + 2 * t;
    int v0 = (i0     < N_NODES) ? cnt[i0]     : 0;
    int v1 = (i0 + 1 < N_NODES) ? cnt[i0 + 1] : 0;
    int s = v0 + v1;
    sdata[t] = s;
    __syncthreads();
    #pragma unroll
    for (int off = 1; off < 256; off <<= 1) {
        int tmp = (t >= off) ? sdata[t - off] : 0;
        __syncthreads();
        sdata[t] += tmp;
        __syncthreads();
    }
    int ex = sdata[t] - s;  // exclusive prefix within chunk
    if (i0     < N_NODES) rowptr[i0]     = ex;
    if (i0 + 1 < N_NODES) rowptr[i0 + 1] = ex + v0;
    if (t == 255) bsum[blockIdx.x] = sdata[255];
}

// phases 2+3 merged: each of the 196 blocks reduces its own chunk offset
// (sum of bsum[0..blk-1], a 196-element reduction) and applies it; also emits
// rowptr_work (the scatter cursor copy).
__global__ __launch_bounds__(256) void scan_p23(int* __restrict__ rowptr,
                                                const int* __restrict__ bsum,
                                                int* __restrict__ rowptr_work)
{
    __shared__ int wsum[4];
    const int t = threadIdx.x;
    int v = (t < (int)blockIdx.x) ? bsum[t] : 0;  // blockIdx.x <= 195 < NCHUNK
    #pragma unroll
    for (int off = 32; off >= 1; off >>= 1) v += __shfl_xor(v, off);
    if ((t & 63) == 0) wsum[t >> 6] = v;
    __syncthreads();
    const int add = wsum[0] + wsum[1] + wsum[2] + wsum[3];
    const int i0 = blockIdx.x * 512 + 2 * t;
    if (i0 < N_NODES) {
        int r = rowptr[i0] + add;
        rowptr[i0] = r; rowptr_work[i0] = r;
    }
    if (i0 + 1 < N_NODES) {
        int r = rowptr[i0 + 1] + add;
        rowptr[i0 + 1] = r; rowptr_work[i0 + 1] = r;
    }
    if (blockIdx.x == 0 && t == 0) rowptr[N_NODES] = N_EDGES;
}

// ---------------------------------------------------------------------------
// CSR build: place src into dst-sorted order (atomic cursor = rowptr_work)
// ---------------------------------------------------------------------------
__global__ void scatter_edges(const int* __restrict__ src, const int* __restrict__ dst,
                              int* __restrict__ rowptr_work,
                              int* __restrict__ sorted_src)
{
    int e = blockIdx.x * blockDim.x + threadIdx.x;
    if (e >= N_EDGES) return;
    int pos = atomicAdd(&rowptr_work[dst[e]], 1);
    sorted_src[pos] = src[e];
}

// ---------------------------------------------------------------------------
// Fused GEMM: [Yl | Yr] = X[100000,1024] @ [W1_l | W1_r]   (bf16 MFMA)
// Tile 128 rows x 256 cols, BK=64, 256 threads (4 waves, 2x2).
// T3/T4 2-phase schedule: stage barrier uses counted vmcnt(8) so the 8
// X-prefetch loads stay in flight across the MFMA phase (never drain to 0).
// ---------------------------------------------------------------------------
__global__ __launch_bounds__(256, 2) void gemm_fused(
    const float* __restrict__ X, const unsigned short* __restrict__ Wcat,
    unsigned short* __restrict__ Ylb, unsigned short* __restrict__ Yrb)
{
    __shared__ unsigned short As[128 * 64];  // [row][chunk^(row&7)] chunks of 8 bf16
    __shared__ unsigned short Bs[256 * 64];  // [n][k] unpadded (glds layout)

    const int tid   = threadIdx.x;
    const int lane  = tid & 63;
    const int wave  = tid >> 6;
    const int waveM = wave >> 1;
    const int waveN = wave & 1;
    const int q     = lane >> 4;
    const int l16   = lane & 15;
    const int esw   = l16 & 7;         // read-side swizzle key
    const int row0  = blockIdx.x * 128;

    const int arow = tid >> 3;          // 0..31 (+32p)
    const int au   = tid & 7;           // A chunk
    const int aesw = arow & 7;          // write-side swizzle key

    f32x4 acc[4][8] = {};
    float4 pre[8];

    // OOB rows (only in the last of 782 blocks) are clamped to row N-1:
    // their MFMA results are garbage-but-finite and masked at the store.
    auto prefetchA = [&](int k0) {
        #pragma unroll
        for (int p = 0; p < 4; ++p) {
            int grow = row0 + p * 32 + arow;
            grow = grow < N_NODES ? grow : (N_NODES - 1);
            const float* gp = &X[(size_t)grow * IN_CH + k0 + au * 8];
            pre[2 * p]     = *(const float4*)gp;
            pre[2 * p + 1] = *(const float4*)(gp + 4);
        }
    };

    prefetchA(0);

    for (int kt = 0; kt < IN_CH / 64; ++kt) {
        const int k0 = kt * 64;

        // ---- B: async global->LDS, 8 issues/wave, 8 rows (1 KB) per issue ----
        #pragma unroll
        for (int i = 0; i < 8; ++i) {
            const int gi = wave * 8 + i;                   // 0..31
            const int r  = gi * 8 + (lane >> 3);
            glds16(&Wcat[(size_t)r * IN_CH + k0 + (lane & 7) * 8],
                   &Bs[gi * 8 * 64]);
        }
        // Pin the 8 glds as the OLDEST outstanding VMEM ops (prefetchA's loads
        // don't alias them, so without this the scheduler could interleave
        // issue order and break the vmcnt(8) count below).
        __builtin_amdgcn_sched_barrier(0);

        // ---- A: native packed f32->bf16 convert, swizzled LDS write ----
        // (reading pre[] forces a wait for the PREVIOUS prefetch only; the
        // glds above stay in flight)
        #pragma unroll
        for (int p = 0; p < 4; ++p) {
            const int row = p * 32 + arow;
            const int c   = au ^ aesw;
            const float4 a = pre[2 * p], b = pre[2 * p + 1];
            bf16x8 o;
            o[0] = (__bf16)a.x; o[1] = (__bf16)a.y;
            o[2] = (__bf16)a.z; o[3] = (__bf16)a.w;
            o[4] = (__bf16)b.x; o[5] = (__bf16)b.y;
            o[6] = (__bf16)b.z; o[7] = (__bf16)b.w;
            *(bf16x8*)&As[row * 64 + c * 8] = o;
        }

        const bool has_next = (kt + 1 < IN_CH / 64);
        if (has_next) prefetchA(k0 + 64);

        // ---- stage -> compute barrier: drain ONLY the glds (8 newest are the
        // X prefetch; they ride through the MFMA phase). lgkmcnt(0) makes the
        // As ds_writes visible workgroup-wide.
        if (has_next) {
            asm volatile("s_waitcnt vmcnt(8) lgkmcnt(0)" ::: "memory");
        } else {
            asm volatile("s_waitcnt vmcnt(0) lgkmcnt(0)" ::: "memory");
        }
        __builtin_amdgcn_s_barrier();
        asm volatile("" ::: "memory");

        // ---- MFMA: 2 k-steps of 32, 4x8 tiles per wave ----
        #pragma unroll
        for (int s = 0; s < 2; ++s) {
            bf16x8 af[4], bfr[8];
            const int kc = q + 4 * s;   // chunk index 0..7
            #pragma unroll
            for (int mi = 0; mi < 4; ++mi) {
                const int m = waveM * 64 + mi * 16 + l16;
                af[mi] = __builtin_bit_cast(
                    bf16x8, *(const ushort8v*)&As[m * 64 + (kc ^ esw) * 8]);
            }
            #pragma unroll
            for (int ni = 0; ni < 8; ++ni) {
                const int n = waveN * 128 + ni * 16 + l16;
                bfr[ni] = __builtin_bit_cast(
                    bf16x8, *(const ushort8v*)&Bs[n * 64 + kc * 8]);
            }
            #pragma unroll
            for (int mi = 0; mi < 4; ++mi)
                #pragma unroll
                for (int ni = 0; ni < 8; ++ni)
                    acc[mi][ni] = __builtin_amdgcn_mfma_f32_16x16x32_bf16(
                        af[mi], bfr[ni], acc[mi][ni], 0, 0, 0);
        }

        // ---- compute -> next-stage barrier: no waitcnt needed (each wave's
        // ds_reads retired before its last MFMA issued; LDS overwrite by the
        // next stage is gated by the barrier alone).
        asm volatile("" ::: "memory");
        __builtin_amdgcn_s_barrier();
        asm volatile("" ::: "memory");
    }

    // ---- epilogue: waveN=0 -> Ylb, waveN=1 -> Yrb (bf16 RNE) ----
    unsigned short* __restrict__ Ybuf = waveN ? Yrb : Ylb;
    #pragma unroll
    for (int mi = 0; mi < 4; ++mi) {
        #pragma unroll
        for (int r = 0; r < 4; ++r) {
            const int grow = row0 + waveM * 64 + mi * 16 + q * 4 + r;
            if (grow < N_NODES) {
                #pragma unroll
                for (int ni = 0; ni < 8; ++ni)
                    Ybuf[(size_t)grow * FEAT_CH + ni * 16 + l16] =
                        f2bf(acc[mi][ni][r]);
            }
        }
    }
}

// ---------------------------------------------------------------------------
// Fused layer-1 aggregation + combine + layer-2 projection.
// One wave per node; lane holds channels 2l, 2l+1 (bf16 inputs, f32 math).
// h = leaky( (sum Yl[src]) / max(deg,1) + Yr[node] + b1 )  (in registers)
// Zl = h @ W2_l, Zr = h @ W2_r  via shuffle reduction.
// ---------------------------------------------------------------------------
__global__ __launch_bounds__(256) void fused_agg(
    const unsigned short* __restrict__ Ylb, const unsigned short* __restrict__ Yrb,
    const int* __restrict__ rowptr, const int* __restrict__ sorted_src,
    const float* __restrict__ b1,
    const float* __restrict__ W2l, const float* __restrict__ W2r,
    float* __restrict__ Zl, float* __restrict__ Zr)
{
    int gid = blockIdx.x * blockDim.x + threadIdx.x;
    int node = gid >> 6;
    if (node >= N_NODES) return;
    int lane = threadIdx.x & 63;

    int beg = rowptr[node], end = rowptr[node + 1];
    float ax = 0.f, ay = 0.f;
    for (int e = beg; e < end; ++e) {
        int s = sorted_src[e];
        ushort2 v = *(const ushort2*)&Ylb[(size_t)s * FEAT_CH + lane * 2];
        ax += bf2f(v.x); ay += bf2f(v.y);
    }
    float invd = 1.0f / fmaxf((float)(end - beg), 1.0f);
    ushort2 yv = *(const ushort2*)&Yrb[(size_t)node * FEAT_CH + lane * 2];
    float2 bb = *(const float2*)&b1[lane * 2];
    float hx = fmaf(ax, invd, bf2f(yv.x)) + bb.x;
    float hy = fmaf(ay, invd, bf2f(yv.y)) + bb.y;
    hx = hx >= 0.f ? hx : NEG_SLOPE * hx;
    hy = hy >= 0.f ? hy : NEG_SLOPE * hy;

    const float* wl = &W2l[lane * 2 * 3];
    const float* wr = &W2r[lane * 2 * 3];
    float z[6];
    #pragma unroll
    for (int c = 0; c < 3; ++c) {
        z[c]     = hx * wl[c] + hy * wl[3 + c];
        z[3 + c] = hx * wr[c] + hy * wr[3 + c];
    }
    #pragma unroll
    for (int off = 32; off >= 1; off >>= 1)
        #pragma unroll
        for (int c = 0; c < 6; ++c)
            z[c] += __shfl_xor(z[c], off);

    if (lane == 0) {
        Zl[node * 3 + 0] = z[0]; Zl[node * 3 + 1] = z[1]; Zl[node * 3 + 2] = z[2];
        Zr[node * 3 + 0] = z[3]; Zr[node * 3 + 1] = z[4]; Zr[node * 3 + 2] = z[5];
    }
}

// ---------------------------------------------------------------------------
// Layer-2 aggregation (gather) + final combine, one thread per node:
// out[n,:] = (sum Zl[src,:]) / max(deg,1) + Zr[n,:] + b2[:]
// ---------------------------------------------------------------------------
__global__ void agg2_final(const float* __restrict__ Zl, const float* __restrict__ Zr,
                           const int* __restrict__ rowptr, const int* __restrict__ sorted_src,
                           const float* __restrict__ b2, float* __restrict__ out)
{
    int node = blockIdx.x * blockDim.x + threadIdx.x;
    if (node >= N_NODES) return;
    int beg = rowptr[node], end = rowptr[node + 1];
    float a0 = 0.f, a1 = 0.f, a2 = 0.f;
    for (int e = beg; e < end; ++e) {
        const float* zp = &Zl[sorted_src[e] * 3];
        a0 += zp[0]; a1 += zp[1]; a2 += zp[2];
    }
    float invd = 1.0f / fmaxf((float)(end - beg), 1.0f);
    out[node * 3 + 0] = fmaf(a0, invd, Zr[node * 3 + 0]) + b2[0];
    out[node * 3 + 1] = fmaf(a1, invd, Zr[node * 3 + 1]) + b2[1];
    out[node * 3 + 2] = fmaf(a2, invd, Zr[node * 3 + 2]) + b2[2];
}

// ---------------------------------------------------------------------------
extern "C" void kernel_launch(void* const* d_in, const int* in_sizes, int n_in,
                              void* d_out, int out_size, void* d_ws, size_t ws_size,
                              hipStream_t stream)
{
    const float* X   = (const float*)d_in[0];
    const int*   e2  = (const int*)d_in[2];     // edges2 [2, E] int32
    const float* W1l = (const float*)d_in[5];
    const float* W1r = (const float*)d_in[6];
    const float* b1  = (const float*)d_in[7];
    const float* W2l = (const float*)d_in[8];
    const float* W2r = (const float*)d_in[9];
    const float* b2  = (const float*)d_in[10];
    const int* src = e2;
    const int* dst = e2 + N_EDGES;

    char* ws = (char*)d_ws;
    size_t off = 0;
    auto alloc = [&](size_t bytes) -> void* {
        void* p = ws + off;
        off += (bytes + 255) & ~(size_t)255;
        return p;
    };
    const size_t NBH = (size_t)N_NODES * FEAT_CH * sizeof(unsigned short);  // 25.6 MB
    unsigned short* Ylb = (unsigned short*)alloc(NBH);
    unsigned short* Yrb = (unsigned short*)alloc(NBH);
    float* Zl = (float*)alloc((size_t)N_NODES * OUT_CH * sizeof(float));
    float* Zr = (float*)alloc((size_t)N_NODES * OUT_CH * sizeof(float));
    unsigned short* Wcat = (unsigned short*)alloc((size_t)256 * IN_CH * 2);
    int* cnt         = (int*)alloc((size_t)N_NODES * sizeof(int));
    int* rowptr      = (int*)alloc((size_t)(N_NODES + 1) * sizeof(int));
    int* rowptr_work = (int*)alloc((size_t)N_NODES * sizeof(int));
    int* bsum        = (int*)alloc((size_t)NCHUNK * sizeof(int));
    int* sorted_src  = (int*)alloc((size_t)N_EDGES * sizeof(int));

    // --- weights + cnt zeroing (no memset dispatches) ---
    wt_kernel<<<(256 * IN_CH + 255) / 256, 256, 0, stream>>>(W1l, W1r, Wcat, cnt);

    // --- CSR (counting sort by dst, parallel scan) ---
    hist_kernel<<<(N_EDGES + 255) / 256, 256, 0, stream>>>(dst, cnt);
    scan_p1<<<NCHUNK, 256, 0, stream>>>(cnt, rowptr, bsum);
    scan_p23<<<NCHUNK, 256, 0, stream>>>(rowptr, bsum, rowptr_work);
    scatter_edges<<<(N_EDGES + 255) / 256, 256, 0, stream>>>(src, dst, rowptr_work,
                                                             sorted_src);

    // --- layer 1 GEMM (fused Yl/Yr, bf16 outputs) ---
    gemm_fused<<<(N_NODES + 127) / 128, 256, 0, stream>>>(X, Wcat, Ylb, Yrb);

    // --- fused aggregation + combine + layer-2 projection ---
    fused_agg<<<(N_NODES * 64) / 256, 256, 0, stream>>>(Ylb, Yrb, rowptr, sorted_src,
                                                        b1, W2l, W2r, Zl, Zr);

    // --- layer-2 aggregation + output ---
    agg2_final<<<(N_NODES + 255) / 256, 256, 0, stream>>>(Zl, Zr, rowptr, sorted_src,
                                                          b2, (float*)d_out);
}